// Round 7
// baseline (273.936 us; speedup 1.0000x reference)
//
#include <hip/hip_runtime.h>
#include <hip/hip_bf16.h>
#include <hip/hip_fp16.h>

// GCN 2-layer: out = Ahat * relu(Ahat*(X W1)+b1) * W2 + b2
// Round 7:
//  - aggregate restructured: one wave per dst row, lanes split into G=F/4
//    groups; each group gathers one edge row as half4 (8B/lane) -> 512B per
//    VMEM instr, 4-8 edges in flight per instr, zero intra-wave divergence.
//    Self-loop = pseudo-edge j==beg-1. Cross-group butterfly via __shfl_xor.
//  - bucket_rowptr + csr_fill merged (one pass less over bedges, one launch).
//  - build pipeline otherwise unchanged (atomic-free bucketed counting sort).

#define N_FEAT_IN 64
#define B2SHIFT 9        // 512 dst nodes per coarse bucket
#define CHUNK 4096       // edges per block in pass A/B

struct alignas(8) half4 { __half2 lo, hi; };

// ---- pass A: per-chunk bucket histogram (LDS, no global atomics) ----
__global__ __launch_bounds__(256) void passA_hist(const int* __restrict__ dst,
                                                  int* __restrict__ H, int E) {
    __shared__ int h[256];
    h[threadIdx.x] = 0;
    __syncthreads();
    int base = blockIdx.x * CHUNK;
    int end = min(base + CHUNK, E);
    for (int i = base + threadIdx.x; i < end; i += 256)
        atomicAdd(&h[dst[i] >> B2SHIFT], 1);
    __syncthreads();
    H[blockIdx.x * 256 + threadIdx.x] = h[threadIdx.x];
}

// ---- col_scan_a: one block per column; exclusive scan over NR rows ----
__global__ __launch_bounds__(512) void col_scan_a(int* __restrict__ H,
                                                  int* __restrict__ ctot, int NR) {
    __shared__ int s[512];
    int b = blockIdx.x;
    int t = threadIdx.x;
    int v = (t < NR) ? H[t * 256 + b] : 0;
    s[t] = v;
    __syncthreads();
    for (int off = 1; off < 512; off <<= 1) {
        int a = (t >= off) ? s[t - off] : 0;
        __syncthreads();
        s[t] += a;
        __syncthreads();
    }
    if (t < NR) H[t * 256 + b] = s[t] - v;
    if (t == 511) ctot[b] = s[511];
}

// ---- col_scan_b: scan column totals -> per-bucket bases; row_ptr[n]=E ----
__global__ __launch_bounds__(256) void col_scan_b(const int* __restrict__ ctot,
                                                  int* __restrict__ cbase,
                                                  int* __restrict__ bbase,
                                                  int* __restrict__ row_ptr,
                                                  int NB, int n, int E) {
    __shared__ int s[256];
    int t = threadIdx.x;
    int v = ctot[t];
    s[t] = v;
    __syncthreads();
    for (int off = 1; off < 256; off <<= 1) {
        int a = (t >= off) ? s[t - off] : 0;
        __syncthreads();
        s[t] += a;
        __syncthreads();
    }
    int e = s[t] - v;
    cbase[t] = e;
    if (t < NB) bbase[t] = e;
    if (t == 0) { bbase[NB] = E; row_ptr[n] = E; }
}

// ---- pass B: place packed edges into private per-chunk runs ----
__global__ __launch_bounds__(256) void passB_place(const int* __restrict__ src,
                                                   const int* __restrict__ dst,
                                                   const int* __restrict__ H,
                                                   const int* __restrict__ cbase,
                                                   unsigned* __restrict__ bedges, int E) {
    __shared__ int cur[256];
    cur[threadIdx.x] = H[blockIdx.x * 256 + threadIdx.x] + cbase[threadIdx.x];
    __syncthreads();
    int base = blockIdx.x * CHUNK;
    int end = min(base + CHUNK, E);
    for (int i = base + threadIdx.x; i < end; i += 256) {
        int d = dst[i];
        int p = atomicAdd(&cur[d >> B2SHIFT], 1);  // LDS atomic
        bedges[p] = ((unsigned)src[i] << B2SHIFT) | (unsigned)(d & 511);
    }
}

// ---- merged: per-bucket hist -> local scan -> row_ptr/dinv -> CSR scatter ----
__global__ __launch_bounds__(256) void bucket_csr(const int* __restrict__ bbase,
                                                  const unsigned* __restrict__ bedges,
                                                  int* __restrict__ row_ptr,
                                                  float* __restrict__ dinv,
                                                  int* __restrict__ csr_src, int n) {
    __shared__ int lh[512];
    __shared__ int cur[512];
    int t = threadIdx.x;
    lh[t] = 0;
    lh[t + 256] = 0;
    __syncthreads();
    int b = blockIdx.x;
    int beg = bbase[b], end = bbase[b + 1];
    for (int i = beg + t; i < end; i += 256)
        atomicAdd(&lh[bedges[i] & 511], 1);
    __syncthreads();
    int c0 = lh[t], c1 = lh[t + 256];
    // 512-wide Hillis-Steele inclusive scan, 2 elems/thread
    for (int off = 1; off < 512; off <<= 1) {
        int a0 = (t >= off) ? lh[t - off] : 0;
        int a1 = (t + 256 >= off) ? lh[t + 256 - off] : 0;
        __syncthreads();
        lh[t] += a0;
        lh[t + 256] += a1;
        __syncthreads();
    }
#pragma unroll
    for (int k = 0; k < 2; ++k) {
        int local = t + k * 256;
        int d = (b << B2SHIFT) + local;
        int c = (k == 0) ? c0 : c1;
        int excl = beg + lh[local] - c;
        cur[local] = excl;
        if (d < n) {
            row_ptr[d] = excl;
            dinv[d] = rsqrtf((float)c + 1.0f);
        }
    }
    __syncthreads();
    for (int i = beg + t; i < end; i += 256) {
        unsigned v = bedges[i];
        int p = atomicAdd(&cur[v & 511], 1);  // LDS atomic
        csr_src[p] = (int)(v >> B2SHIFT);
    }
}

// ---- GEMM: outh[n,FO] = half( dinv[row] * (preop(A[n,64]) * W[64,FO]) ) ----
template <int FO, bool RELU_BIAS>
__global__ __launch_bounds__(256) void gemm_rows(const float* __restrict__ A,
                                                 const float* __restrict__ W,
                                                 const float* __restrict__ bias,
                                                 const float* __restrict__ dinv,
                                                 __half* __restrict__ outh, int n) {
    constexpr int K = 64;
    constexpr int CPT = FO / 4;
    __shared__ float As[64][K + 4];
    __shared__ float Ws[K][FO];

    const int t = threadIdx.x;
    const int r0 = blockIdx.x * 64;

    constexpr int W4 = K * FO / 4;
    for (int i = t; i < W4; i += 256) {
        int k = i / (FO / 4);
        int c4 = (i % (FO / 4)) * 4;
        *(float4*)&Ws[k][c4] = *(const float4*)&W[k * FO + c4];
    }
    for (int i = t; i < 1024; i += 256) {
        int row = i / 16;
        int c4 = (i % 16) * 4;
        int g = r0 + row;
        float4 v = make_float4(0.f, 0.f, 0.f, 0.f);
        if (g < n) {
            v = *(const float4*)&A[(size_t)g * K + c4];
            if (RELU_BIAS) {
                v.x = fmaxf(v.x + bias[c4 + 0], 0.f);
                v.y = fmaxf(v.y + bias[c4 + 1], 0.f);
                v.z = fmaxf(v.z + bias[c4 + 2], 0.f);
                v.w = fmaxf(v.w + bias[c4 + 3], 0.f);
            }
        }
        *(float4*)&As[row][c4] = v;
    }
    __syncthreads();

    const int row = t >> 2;
    const int c0 = (t & 3) * CPT;
    float acc[CPT];
#pragma unroll
    for (int j = 0; j < CPT; ++j) acc[j] = 0.f;

#pragma unroll
    for (int k = 0; k < K; ++k) {
        float xv = As[row][k];
#pragma unroll
        for (int j = 0; j < CPT; ++j) acc[j] = fmaf(xv, Ws[k][c0 + j], acc[j]);
    }

    int g = r0 + row;
    if (g < n) {
        float sc = dinv[g];
#pragma unroll
        for (int j4 = 0; j4 < CPT; j4 += 4) {
            half4 h;
            h.lo = __floats2half2_rn(acc[j4] * sc, acc[j4 + 1] * sc);
            h.hi = __floats2half2_rn(acc[j4 + 2] * sc, acc[j4 + 3] * sc);
            *(half4*)&outh[(size_t)g * FO + c0 + j4] = h;
        }
    }
}

// ---- wide-gather pull aggregation ----
// One 64-lane wave per dst row. Lanes split into EPW = 64/(F/4) groups; group
// g handles edge slot g of each batch with half4 loads (8B/lane). Self-loop is
// pseudo-edge j == beg-1. Butterfly-sum across groups, group 0 writes fp32 row.
template <int F, bool ADD_BIAS>
__global__ __launch_bounds__(256) void aggregate(const int* __restrict__ row_ptr,
                                                 const int* __restrict__ csr_src,
                                                 const float* __restrict__ dinv,
                                                 const __half* __restrict__ xs,
                                                 const float* __restrict__ bias,
                                                 float* __restrict__ out, int n) {
    constexpr int G = F / 4;       // lanes per edge-group (16 or 8)
    constexpr int EPW = 64 / G;    // edges per wave-step (4 or 8)
    int d = blockIdx.x * 4 + (threadIdx.x >> 6);   // one wave per row
    if (d >= n) return;
    int lane = threadIdx.x & 63;
    int g = lane / G;              // edge slot within batch
    int c = lane % G;              // half4 column (features 4c..4c+3)

    int beg = row_ptr[d];
    int end = row_ptr[d + 1];

    float4 acc = make_float4(0.f, 0.f, 0.f, 0.f);
#pragma unroll 2
    for (int jb = beg - 1; jb < end; jb += EPW) {
        int j = jb + g;
        int idx = (j == beg - 1) ? d : ((j < end) ? csr_src[j] : -1);
        if (idx >= 0) {
            half4 h = *(const half4*)&xs[(size_t)idx * F + 4 * c];
            float2 lo = __half22float2(h.lo);
            float2 hi = __half22float2(h.hi);
            acc.x += lo.x;
            acc.y += lo.y;
            acc.z += hi.x;
            acc.w += hi.y;
        }
    }
    // butterfly over the group bits (G..32)
#pragma unroll
    for (int off = G; off < 64; off <<= 1) {
        acc.x += __shfl_xor(acc.x, off);
        acc.y += __shfl_xor(acc.y, off);
        acc.z += __shfl_xor(acc.z, off);
        acc.w += __shfl_xor(acc.w, off);
    }
    if (g == 0) {
        float sc = dinv[d];
        float4 r;
        r.x = acc.x * sc;
        r.y = acc.y * sc;
        r.z = acc.z * sc;
        r.w = acc.w * sc;
        if (ADD_BIAS) {
            r.x += bias[4 * c + 0];
            r.y += bias[4 * c + 1];
            r.z += bias[4 * c + 2];
            r.w += bias[4 * c + 3];
        }
        *(float4*)&out[(size_t)d * F + 4 * c] = r;
    }
}

extern "C" void kernel_launch(void* const* d_in, const int* in_sizes, int n_in,
                              void* d_out, int out_size, void* d_ws, size_t ws_size,
                              hipStream_t stream) {
    const float* x  = (const float*)d_in[0];   // [n, 64]
    const int*   ei = (const int*)d_in[1];     // [2, E]
    const float* W1 = (const float*)d_in[2];   // [64, 64]
    const float* b1 = (const float*)d_in[3];   // [64]
    const float* W2 = (const float*)d_in[4];   // [64, 32]
    const float* b2 = (const float*)d_in[5];   // [32]
    float* out = (float*)d_out;                // [n, 32]

    const int n = in_sizes[0] / N_FEAT_IN;     // 100000
    const int E = in_sizes[1] / 2;             // 1600000
    const int* srcI = ei;
    const int* dstI = ei + E;

    const int NB = (n + 511) >> B2SHIFT;       // 196 coarse buckets
    const int NR = (E + CHUNK - 1) / CHUNK;    // 391 chunks

    // workspace layout (256B aligned)
    char* ws = (char*)d_ws;
    size_t off = 0;
    auto alloc = [&](size_t bytes) {
        void* p = ws + off;
        off += (bytes + 255) & ~(size_t)255;
        return p;
    };
    float*    dinv    = (float*)alloc((size_t)n * 4);
    int*      row_ptr = (int*)alloc((size_t)(n + 1) * 4);
    int*      bbase   = (int*)alloc((size_t)(NB + 1) * 4);
    int*      ctot    = (int*)alloc((size_t)256 * 4);
    int*      cbase   = (int*)alloc((size_t)256 * 4);
    int*      H       = (int*)alloc((size_t)NR * 256 * 4);   // ~400KB
    unsigned* bedges  = (unsigned*)alloc((size_t)E * 4);
    int*      csr_src = (int*)alloc((size_t)E * 4);
    __half*   xs      = (__half*)alloc((size_t)n * 64 * 2);  // fp16 gather table
    float*    agg1    = (float*)alloc((size_t)n * 64 * 4);

    // 1) atomic-free bucket sort by dst>>9
    passA_hist<<<NR, 256, 0, stream>>>(dstI, H, E);
    col_scan_a<<<256, 512, 0, stream>>>(H, ctot, NR);
    col_scan_b<<<1, 256, 0, stream>>>(ctot, cbase, bbase, row_ptr, NB, n, E);
    passB_place<<<NR, 256, 0, stream>>>(srcI, dstI, H, cbase, bedges, E);

    // 2) merged: row_ptr + dinv + CSR scatter
    bucket_csr<<<NB, 256, 0, stream>>>(bbase, bedges, row_ptr, dinv, csr_src, n);

    // 3) layer 1: xs = half(dinv .* (X W1)); agg1 = dinv .* (gather-sum + self)
    gemm_rows<64, false><<<(n + 63) / 64, 256, 0, stream>>>(x, W1, nullptr, dinv, xs, n);
    aggregate<64, false><<<(n + 3) / 4, 256, 0, stream>>>(row_ptr, csr_src, dinv, xs, nullptr, agg1, n);

    // 4) layer 2: xs2 = half(dinv .* (relu(agg1+b1) W2)); out = dinv .* (...) + b2
    gemm_rows<32, true><<<(n + 63) / 64, 256, 0, stream>>>(agg1, W2, b1, dinv, xs, n);
    aggregate<32, true><<<(n + 3) / 4, 256, 0, stream>>>(row_ptr, csr_src, dinv, xs, b2, out, n);
}